// Round 10
// baseline (673.975 us; speedup 1.0000x reference)
//
#include <hip/hip_runtime.h>
#include <hip/hip_bf16.h>

// Problem constants (from reference)
#define N_NODES 50000
#define N_EDGES 640000
#define F_IN 64
#define EDGE_DIM 16
#define HID 128
#define N_LAYERS 3
#define NUM_GRAPHS 64
#define BN_EPS 1e-5f

typedef __attribute__((ext_vector_type(8))) short short8;    // 8 bf16 (4 VGPRs)
typedef __attribute__((ext_vector_type(4))) float f32x4;     // MFMA acc
typedef __attribute__((ext_vector_type(2))) __fp16 half2v;   // packed f16 pair (builtin type)

// bf16 <-> f32 helpers (manual, RNE on pack)
__device__ __forceinline__ float bfl(unsigned int u) {
    unsigned int v = u << 16; float f; __builtin_memcpy(&f, &v, 4); return f;
}
__device__ __forceinline__ float bfh(unsigned int u) {
    unsigned int v = u & 0xffff0000u; float f; __builtin_memcpy(&f, &v, 4); return f;
}
__device__ __forceinline__ unsigned int f2bf(float f) {
    unsigned int v; __builtin_memcpy(&v, &f, 4);
    v += 0x7fffu + ((v >> 16) & 1u);
    return v >> 16;
}
__device__ __forceinline__ unsigned int pack2(float lo, float hi) {
    return f2bf(lo) | (f2bf(hi) << 16);
}
__device__ __forceinline__ half2v u2h(unsigned int u) {
    half2v h; __builtin_memcpy(&h, &u, 4); return h;
}
__device__ __forceinline__ unsigned int pkh(float a, float b) {
    half2v h = __builtin_amdgcn_cvt_pkrtz(a, b);
    unsigned int u; __builtin_memcpy(&u, &h, 4); return u;
}

// ---------------------------------------------------------------------------
// Degree histogram (row_ptr must be pre-zeroed by k_pack)
// ---------------------------------------------------------------------------
__global__ void k_hist(const int* __restrict__ dst, int* __restrict__ deg) {
    int e = blockIdx.x * 256 + threadIdx.x;   // grid exact: 2500*256 = 640000
    atomicAdd(&deg[dst[e]], 1);
}

// ---------------------------------------------------------------------------
// Single-block exclusive scan of deg[0..N_NODES) -> row_ptr + cursor copy.
// 1024 threads, 49 contiguous elements per thread (1024*49 = 50176).
// ---------------------------------------------------------------------------
#define SCAN_CH 49
__global__ __launch_bounds__(1024) void k_scan(int* __restrict__ rp,
                                               int* __restrict__ cursor) {
    __shared__ int s[1024];
    const int tid = threadIdx.x;
    const int base = tid * SCAN_CH;
    int loc[SCAN_CH];
    int sum = 0;
#pragma unroll
    for (int j = 0; j < SCAN_CH; ++j) {
        const int i = base + j;
        const int v = (i < N_NODES) ? rp[i] : 0;
        loc[j] = sum;
        sum += v;
    }
    s[tid] = sum;
    __syncthreads();
    for (int off = 1; off < 1024; off <<= 1) {
        int t = 0;
        if (tid >= off) t = s[tid - off];
        __syncthreads();
        s[tid] += t;
        __syncthreads();
    }
    const int offset = s[tid] - sum;   // exclusive prefix of this thread's chunk
#pragma unroll
    for (int j = 0; j < SCAN_CH; ++j) {
        const int i = base + j;
        if (i < N_NODES) {
            const int e = offset + loc[j];
            rp[i] = e;
            cursor[i] = e;
        }
    }
    if (tid == 0) rp[N_NODES] = N_EDGES;
}

// ---------------------------------------------------------------------------
// Fused fill + materialize: for each original edge e (coalesced reads!),
// claim CSR slot p = cursor[dst]++ and scatter-write src_s[p] and the
// f16-pair packed edge attributes. No elist, no random reads.
// ---------------------------------------------------------------------------
__global__ __launch_bounds__(256) void k_fillg(const int* __restrict__ esrc,
                                               const int* __restrict__ edst,
                                               const float* __restrict__ eattr,
                                               int* __restrict__ cursor,
                                               int* __restrict__ src_s,
                                               uint4* __restrict__ eattr_h) {
    const int e = blockIdx.x * 256 + threadIdx.x;   // exact: 2500*256
    const int d = edst[e];
    const int sv = esrc[e];
    const float* ep = eattr + (size_t)e * EDGE_DIM;
    const float4 a0 = *(const float4*)ep;
    const float4 a1 = *(const float4*)(ep + 4);
    const float4 a2 = *(const float4*)(ep + 8);
    const float4 a3 = *(const float4*)(ep + 12);
    const int p = atomicAdd(&cursor[d], 1);
    src_s[p] = sv;
    eattr_h[p * 2] = make_uint4(pkh(a0.x, a0.y), pkh(a0.z, a0.w),
                                pkh(a1.x, a1.y), pkh(a1.z, a1.w));
    eattr_h[p * 2 + 1] = make_uint4(pkh(a2.x, a2.y), pkh(a2.z, a2.w),
                                    pkh(a3.x, a3.y), pkh(a3.z, a3.w));
}

// ---------------------------------------------------------------------------
// Merged weight packing + workspace zeroing:
// [0,12288) W1/W2 MFMA B-frags; [12288,13312) enc_W B-frags;
// [13312,16384) edge-weight f16 pairs; [16384,24576) zero g;
// [24576,74577) zero row_ptr.  Grid 292*256 = 74752.
// ---------------------------------------------------------------------------
__global__ void k_pack(const float* __restrict__ W1, const float* __restrict__ W2,
                       const float* __restrict__ encW, const float* __restrict__ eW,
                       unsigned short* __restrict__ wp, unsigned short* __restrict__ wpe,
                       unsigned int* __restrict__ wek, float* __restrict__ g,
                       int* __restrict__ row_ptr) {
    const int t = blockIdx.x * 256 + threadIdx.x;
    if (t < 12288) {
        const int mat = t >> 11;
        const int r = t & 2047;
        const int kstep = r >> 9;
        const int ntile = (r >> 6) & 7;
        const int lane = r & 63;
        const float* W = (mat < 3) ? (W1 + mat * 16384) : (W2 + (mat - 3) * 16384);
        const int kbase = kstep * 32 + ((lane >> 4) << 3);
        const int n = ntile * 16 + (lane & 15);
        unsigned int o[4];
#pragma unroll
        for (int jj = 0; jj < 4; ++jj)
            o[jj] = pack2(W[(kbase + 2 * jj) * HID + n], W[(kbase + 2 * jj + 1) * HID + n]);
        *(uint4*)(wp + (size_t)mat * 16384 + (((kstep << 3) + ntile) * 64 + lane) * 8) =
            make_uint4(o[0], o[1], o[2], o[3]);
    } else if (t < 13312) {
        const int r = t - 12288;
        const int kstep = r >> 9;
        const int ntile = (r >> 6) & 7;
        const int lane = r & 63;
        const int kbase = kstep * 32 + ((lane >> 4) << 3);
        const int n = ntile * 16 + (lane & 15);
        unsigned int o[4];
#pragma unroll
        for (int jj = 0; jj < 4; ++jj)
            o[jj] = pack2(encW[(kbase + 2 * jj) * HID + n], encW[(kbase + 2 * jj + 1) * HID + n]);
        *(uint4*)(wpe + (((kstep << 3) + ntile) * 64 + lane) * 8) =
            make_uint4(o[0], o[1], o[2], o[3]);
    } else if (t < 16384) {
        const int r = t - 13312;                    // 0..3071
        const int l = r >> 10;
        const int rr = r & 1023;
        const int kp = rr >> 7, f = rr & 127;
        const float a = eW[(l * EDGE_DIM + 2 * kp) * HID + f];
        const float b = eW[(l * EDGE_DIM + 2 * kp + 1) * HID + f];
        wek[r] = pkh(a, b);
    } else if (t < 24576) {
        g[t - 16384] = 0.f;
    } else if (t < 24576 + N_NODES + 1) {
        row_ptr[t - 24576] = 0;
    }
}

// ---------------------------------------------------------------------------
// Encoder via MFMA: hb = bf16(x @ enc_W + enc_b), reads fp32 x directly.
// ---------------------------------------------------------------------------
__global__ __launch_bounds__(256, 3) void k_encm(const float* __restrict__ x,
                                                 const unsigned short* __restrict__ wpe,
                                                 const float* __restrict__ b,
                                                 unsigned short* __restrict__ hb) {
    const int tid = threadIdx.x;
    const int w = tid >> 6, lane = tid & 63;
    const int q = lane >> 4, l15 = lane & 15;
    const int row0 = blockIdx.x * 64 + w * 16;
    const int ar = min(row0 + l15, N_NODES - 1);
    const float* xp = x + (size_t)ar * F_IN + q * 8;
    f32x4 acc[8];
#pragma unroll
    for (int nt = 0; nt < 8; ++nt) acc[nt] = (f32x4){0.f, 0.f, 0.f, 0.f};
#pragma unroll
    for (int ks = 0; ks < 2; ++ks) {
        const float4 v0 = *(const float4*)(xp + ks * 32);
        const float4 v1 = *(const float4*)(xp + ks * 32 + 4);
        unsigned int u[4] = {pack2(v0.x, v0.y), pack2(v0.z, v0.w),
                             pack2(v1.x, v1.y), pack2(v1.z, v1.w)};
        short8 a; __builtin_memcpy(&a, u, 16);
#pragma unroll
        for (int nt = 0; nt < 8; ++nt) {
            const short8 bf = *(const short8*)(wpe + (((ks << 3) + nt) * 64 + lane) * 8);
            acc[nt] = __builtin_amdgcn_mfma_f32_16x16x32_bf16(a, bf, acc[nt], 0, 0, 0);
        }
    }
    const int rowb = row0 + q * 4;
#pragma unroll
    for (int nt = 0; nt < 8; ++nt) {
        const float bias = b[nt * 16 + l15];
        const int cc = nt * 16 + l15;
#pragma unroll
        for (int reg = 0; reg < 4; ++reg) {
            const int r = rowb + reg;
            if (r < N_NODES)
                hb[(size_t)r * HID + cc] = (unsigned short)f2bf(acc[nt][reg] + bias);
        }
    }
}

// ---------------------------------------------------------------------------
// GINE aggregation v10 (r9 body, measured-stable): one wave per node,
// fused BN+ReLU affine of the previous layer, f16 dot2 edge-MLP,
// chunk-of-4 with depth-2 gather pipeline pinned by sched_barrier(0).
// Block 0 additionally zeroes the NEXT BN accumulator (bnz) so the
// per-layer hipMemsetAsync is eliminated.
// ---------------------------------------------------------------------------
__global__ __launch_bounds__(256, 2) void k_agg(const unsigned int* __restrict__ in32,
                                                const int* __restrict__ src_s,
                                                const uint4* __restrict__ eattr_h,
                                                const unsigned int* __restrict__ wek,
                                                const float* __restrict__ be,
                                                const int* __restrict__ row_ptr,
                                                const float* __restrict__ bnst,
                                                const float* __restrict__ gamma,
                                                const float* __restrict__ beta,
                                                const int bnmode,
                                                float* __restrict__ bnz,
                                                unsigned int* __restrict__ zb32) {
    if (blockIdx.x == 0) bnz[threadIdx.x] = 0.f;   // zero next-layer BN accum (256 floats)

    const int lane = threadIdx.x & 63;
    const int wv = threadIdx.x >> 6;
    const int f2 = lane * 2;
    half2v wx[8], wy[8];
#pragma unroll
    for (int j = 0; j < 8; ++j) {
        wx[j] = u2h(wek[j * 128 + f2]);
        wy[j] = u2h(wek[j * 128 + f2 + 1]);
    }
    const float2 eb = *(const float2*)&be[f2];

    // fused BN(prev layer)+ReLU affine
    float2 sc = make_float2(1.f, 1.f), sh = make_float2(0.f, 0.f);
    float rlo = -3.4e38f;
    if (bnmode) {
        const float invN = 1.0f / (float)N_NODES;
        const float m0 = bnst[f2] * invN, m1 = bnst[f2 + 1] * invN;
        const float v0 = fmaxf(bnst[128 + f2] * invN - m0 * m0, 0.f);
        const float v1 = fmaxf(bnst[128 + f2 + 1] * invN - m1 * m1, 0.f);
        const float r0 = rsqrtf(v0 + BN_EPS), r1 = rsqrtf(v1 + BN_EPS);
        sc = make_float2(gamma[f2] * r0, gamma[f2 + 1] * r1);
        sh = make_float2(fmaf(-m0, sc.x, beta[f2]), fmaf(-m1, sc.y, beta[f2 + 1]));
        rlo = 0.f;
    }

    const int n = blockIdx.x * 4 + wv;        // grid exact: 12500*4 = 50000
    const int base = __builtin_amdgcn_readfirstlane(row_ptr[n]);
    const int deg = __builtin_amdgcn_readfirstlane(row_ptr[n + 1]) - base;

    const unsigned int uself = in32[n * 64 + lane];
    float2 acc = make_float2(fmaxf(fmaf(bfl(uself), sc.x, sh.x), rlo),
                             fmaxf(fmaf(bfh(uself), sc.y, sh.y), rlo));

    if (deg > 0) {
        const int* sp = src_s + base;
        const uint4* ep = eattr_h + (size_t)base * 2;
        const int last = deg - 1;
        const int nch = (deg + 3) >> 2;

        unsigned int huC[4], huN[4];
        uint4 eaC[4][2], eaN[4][2];
        int s2[4];
        {
            int s0[4], s1[4];
#pragma unroll
            for (int j = 0; j < 4; ++j) s0[j] = sp[min(j, last)];
#pragma unroll
            for (int j = 0; j < 4; ++j) huC[j] = in32[s0[j] * 64 + lane];
#pragma unroll
            for (int j = 0; j < 4; ++j) s1[j] = sp[min(4 + j, last)];
            if (nch > 1) {
#pragma unroll
                for (int j = 0; j < 4; ++j) huN[j] = in32[s1[j] * 64 + lane];
            } else {
#pragma unroll
                for (int j = 0; j < 4; ++j) huN[j] = 0u;
            }
#pragma unroll
            for (int j = 0; j < 4; ++j) {
                const int e = min(j, last);
                eaC[j][0] = ep[e * 2]; eaC[j][1] = ep[e * 2 + 1];
            }
#pragma unroll
            for (int j = 0; j < 4; ++j) s2[j] = sp[min(8 + j, last)];
        }
        for (int c = 0; c < nch; ++c) {
            // ---- issue section: gathers for c+2, srcs for c+3, attrs c+1 ----
            unsigned int huNN[4] = {0u, 0u, 0u, 0u};
            if (c + 2 < nch) {
#pragma unroll
                for (int j = 0; j < 4; ++j) huNN[j] = in32[s2[j] * 64 + lane];
            }
            int s3[4];
#pragma unroll
            for (int j = 0; j < 4; ++j) s3[j] = sp[min((c + 3) * 4 + j, last)];
            if (c + 1 < nch) {
#pragma unroll
                for (int j = 0; j < 4; ++j) {
                    const int e = min((c + 1) * 4 + j, last);
                    eaN[j][0] = ep[e * 2]; eaN[j][1] = ep[e * 2 + 1];
                }
            }
            // pin: keep the issue section ABOVE the compute section
            __builtin_amdgcn_sched_barrier(0);
            // ---- compute chunk c ----
            const int rem = deg - c * 4;
#pragma unroll
            for (int j = 0; j < 4; ++j) {
                if (j < rem) {
                    const unsigned int* au = (const unsigned int*)&eaC[j][0];
                    float ex = eb.x, ey = eb.y;
#pragma unroll
                    for (int k = 0; k < 8; ++k) {
                        const half2v a = u2h(au[k]);
                        ex = __builtin_amdgcn_fdot2(a, wx[k], ex, false);
                        ey = __builtin_amdgcn_fdot2(a, wy[k], ey, false);
                    }
                    const float hx = fmaxf(fmaf(bfl(huC[j]), sc.x, sh.x), rlo);
                    const float hy = fmaxf(fmaf(bfh(huC[j]), sc.y, sh.y), rlo);
                    acc.x += fmaxf(hx + ex, 0.f);
                    acc.y += fmaxf(hy + ey, 0.f);
                }
            }
            // rotate pipeline
            if (c + 1 < nch) {
#pragma unroll
                for (int j = 0; j < 4; ++j) {
                    huC[j] = huN[j]; huN[j] = huNN[j];
                    eaC[j][0] = eaN[j][0]; eaC[j][1] = eaN[j][1];
                    s2[j] = s3[j];
                }
            }
        }
    }
    zb32[n * 64 + lane] = pack2(acc.x, acc.y);
}

// ---------------------------------------------------------------------------
// Fused node MLP via bf16 MFMA (16x16x32): z2b = bf16(relu(z@W1+b1)@W2+b2),
// plus BN sum/sumsq partials (fp32, from accumulators).
// ---------------------------------------------------------------------------
#define Z1LD 136

__global__ __launch_bounds__(256, 3) void k_mlp(const unsigned short* __restrict__ zb,
                                                const unsigned short* __restrict__ w1p,
                                                const float* __restrict__ b1,
                                                const unsigned short* __restrict__ w2p,
                                                const float* __restrict__ b2,
                                                unsigned short* __restrict__ z2b,
                                                float* __restrict__ bn) {
    __shared__ unsigned short z1s[64 * Z1LD];
    __shared__ float redA[512];
    __shared__ float redB[512];
    const int tid = threadIdx.x;
    const int w = tid >> 6, lane = tid & 63;
    const int q = lane >> 4, l15 = lane & 15;
    const int row0 = blockIdx.x * 64 + w * 16;

    const int ar = min(row0 + l15, N_NODES - 1);
    const unsigned short* aptr = zb + (size_t)ar * HID + q * 8;

    f32x4 acc[8];
#pragma unroll
    for (int nt = 0; nt < 8; ++nt) acc[nt] = (f32x4){0.f, 0.f, 0.f, 0.f};

#pragma unroll
    for (int ks = 0; ks < 4; ++ks) {
        const short8 a = *(const short8*)(aptr + ks * 32);
#pragma unroll
        for (int nt = 0; nt < 8; ++nt) {
            const short8 b = *(const short8*)(w1p + (((ks << 3) + nt) * 64 + lane) * 8);
            acc[nt] = __builtin_amdgcn_mfma_f32_16x16x32_bf16(a, b, acc[nt], 0, 0, 0);
        }
    }
    {
        const int lr0 = w * 16 + q * 4;
#pragma unroll
        for (int nt = 0; nt < 8; ++nt) {
            const float bias = b1[nt * 16 + l15];
            const int cc = nt * 16 + l15;
#pragma unroll
            for (int reg = 0; reg < 4; ++reg) {
                const float v = fmaxf(acc[nt][reg] + bias, 0.f);
                z1s[(lr0 + reg) * Z1LD + cc] = (unsigned short)f2bf(v);
            }
        }
    }
#pragma unroll
    for (int nt = 0; nt < 8; ++nt) acc[nt] = (f32x4){0.f, 0.f, 0.f, 0.f};
    const unsigned short* a2p = &z1s[(w * 16 + l15) * Z1LD + q * 8];
#pragma unroll
    for (int ks = 0; ks < 4; ++ks) {
        const short8 a = *(const short8*)(a2p + ks * 32);
#pragma unroll
        for (int nt = 0; nt < 8; ++nt) {
            const short8 b = *(const short8*)(w2p + (((ks << 3) + nt) * 64 + lane) * 8);
            acc[nt] = __builtin_amdgcn_mfma_f32_16x16x32_bf16(a, b, acc[nt], 0, 0, 0);
        }
    }
    float s[8], sq[8];
    const int rowb = row0 + q * 4;
#pragma unroll
    for (int nt = 0; nt < 8; ++nt) {
        const float bias = b2[nt * 16 + l15];
        const int cc = nt * 16 + l15;
        float ls = 0.f, lq = 0.f;
#pragma unroll
        for (int reg = 0; reg < 4; ++reg) {
            const int r = rowb + reg;
            const float v = acc[nt][reg] + bias;
            if (r < N_NODES) {
                z2b[(size_t)r * HID + cc] = (unsigned short)f2bf(v);
                ls += v;
                lq = fmaf(v, v, lq);
            }
        }
        s[nt] = ls; sq[nt] = lq;
    }
#pragma unroll
    for (int nt = 0; nt < 8; ++nt) {
        s[nt] += __shfl_xor(s[nt], 16, 64);
        s[nt] += __shfl_xor(s[nt], 32, 64);
        sq[nt] += __shfl_xor(sq[nt], 16, 64);
        sq[nt] += __shfl_xor(sq[nt], 32, 64);
    }
    if (lane < 16) {
#pragma unroll
        for (int nt = 0; nt < 8; ++nt) {
            redA[w * 128 + nt * 16 + lane] = s[nt];
            redB[w * 128 + nt * 16 + lane] = sq[nt];
        }
    }
    __syncthreads();
    if (tid < 128) {
        float t = redA[tid] + redA[128 + tid] + redA[256 + tid] + redA[384 + tid];
        atomicAdd(&bn[tid], t);
    } else {
        const int c = tid - 128;
        float t = redB[c] + redB[128 + c] + redB[256 + c] + redB[384 + c];
        atomicAdd(&bn[128 + c], t);
    }
}

// ---------------------------------------------------------------------------
// Global add pool (batch sorted), with fused BN+ReLU of the last layer.
// ---------------------------------------------------------------------------
__global__ void k_pool(const unsigned short* __restrict__ z2b, const int* __restrict__ batch,
                       const float* __restrict__ bnst, const float* __restrict__ gamma,
                       const float* __restrict__ beta, float* __restrict__ g) {
    const int f = threadIdx.x;            // 128 threads
    const float invN = 1.0f / (float)N_NODES;
    const float m = bnst[f] * invN;
    const float var = fmaxf(bnst[128 + f] * invN - m * m, 0.f);
    const float r = rsqrtf(var + BN_EPS);
    const float sc = gamma[f] * r;
    const float sh = fmaf(-m, sc, beta[f]);

    const int n0 = blockIdx.x * 128;
    const int nend = min(n0 + 128, N_NODES);
    float acc = 0.f;
    int cur = batch[n0];
    for (int n = n0; n < nend; ++n) {
        const int bb = batch[n];
        if (bb != cur) {
            atomicAdd(&g[cur * HID + f], acc);
            acc = 0.f;
            cur = bb;
        }
        const float raw = bfl((unsigned int)z2b[n * HID + f]);
        acc += fmaxf(fmaf(raw, sc, sh), 0.f);
    }
    atomicAdd(&g[cur * HID + f], acc);
}

// ---------------------------------------------------------------------------
// Head: out = relu(g @ hW1 + hb1) @ hW2 + hb2, single block of 1024.
// ---------------------------------------------------------------------------
__global__ __launch_bounds__(1024) void k_head(const float* __restrict__ g,
                                               const float* __restrict__ W1h,
                                               const float* __restrict__ b1h,
                                               const float* __restrict__ W2h,
                                               const float* __restrict__ b2h,
                                               float* __restrict__ out) {
    __shared__ float g1s[NUM_GRAPHS * HID];
    const int tid = threadIdx.x;
#pragma unroll
    for (int i = 0; i < 8; ++i) {
        const int idx = i * 1024 + tid;       // 8192 outputs
        const int r = idx >> 7, c = idx & 127;
        float acc = b1h[c];
        for (int k = 0; k < 128; ++k) acc = fmaf(g[r * HID + k], W1h[k * HID + c], acc);
        g1s[idx] = fmaxf(acc, 0.f);
    }
    __syncthreads();
    if (tid < NUM_GRAPHS * 2) {
        const int r = tid >> 1, c = tid & 1;
        float acc = b2h[c];
        for (int k = 0; k < 128; ++k) acc = fmaf(g1s[r * HID + k], W2h[k * 2 + c], acc);
        out[tid] = acc;
    }
}

// ---------------------------------------------------------------------------
// Launch — 13 dispatches total
// ---------------------------------------------------------------------------
extern "C" void kernel_launch(void* const* d_in, const int* in_sizes, int n_in,
                              void* d_out, int out_size, void* d_ws, size_t ws_size,
                              hipStream_t stream) {
    const float* x     = (const float*)d_in[0];
    const int*   ei    = (const int*)d_in[1];
    const float* eattr = (const float*)d_in[2];
    const int*   batch = (const int*)d_in[3];
    const float* encW  = (const float*)d_in[4];
    const float* encb  = (const float*)d_in[5];
    const float* eW    = (const float*)d_in[6];
    const float* eb    = (const float*)d_in[7];
    const float* W1    = (const float*)d_in[8];
    const float* b1    = (const float*)d_in[9];
    const float* W2    = (const float*)d_in[10];
    const float* b2    = (const float*)d_in[11];
    const float* gam   = (const float*)d_in[12];
    const float* bet   = (const float*)d_in[13];
    const float* hW1   = (const float*)d_in[14];
    const float* hb1   = (const float*)d_in[15];
    const float* hW2   = (const float*)d_in[16];
    const float* hb2   = (const float*)d_in[17];
    float* out = (float*)d_out;

    // workspace layout (float-sized slots)
    float* ws = (float*)d_ws;
    unsigned short* z2b = (unsigned short*)ws;              // 6.4M u16 = 3.2M floats
    float* bn0 = ws + 3200000;              // 256
    float* bn1 = ws + 3200256;              // 256
    float* g   = ws + 3200512;              // 8,192
    unsigned short* hb = (unsigned short*)(ws + 3216640);   // 6.4M u16
    unsigned int* zb32 = (unsigned int*)(ws + 6416640);     // 6.4M u16
    int* row_ptr = (int*)(ws + 11216640);   // 50,001
    int* cursor  = row_ptr + N_NODES + 1;   // 50,000
    int* src_s   = cursor + N_NODES;        // 640,000
    uint4* eattr_h = (uint4*)(ws + 12596900);               // 5.12M u32
    unsigned short* wp  = (unsigned short*)(ws + 17716900); // 98,304 u16
    unsigned short* wpe = (unsigned short*)(ws + 17766100); // 8,192 u16
    unsigned int*   wek = (unsigned int*)(ws + 17770200);   // 3,072 u32

    const int* esrc = ei;
    const int* edst = ei + N_EDGES;

    // pack weights + zero row_ptr/g (replaces 2 memsets)
    k_pack<<<292, 256, 0, stream>>>(W1, W2, encW, eW, wp, wpe, wek, g, row_ptr);
    // CSR build (fused): hist -> single-block scan -> fill+materialize
    k_hist<<<N_EDGES / 256, 256, 0, stream>>>(edst, row_ptr);
    k_scan<<<1, 1024, 0, stream>>>(row_ptr, cursor);
    k_fillg<<<N_EDGES / 256, 256, 0, stream>>>(esrc, edst, eattr, cursor, src_s, eattr_h);

    // encoder -> bf16 h (MFMA, reads fp32 x directly)
    k_encm<<<782, 256, 0, stream>>>(x, wpe, encb, hb);

    // per layer: agg (fused prev-BN+ReLU, zeroes next bn buffer) -> mlp
    float* bnbuf[2] = {bn0, bn1};
    for (int l = 0; l < N_LAYERS; ++l) {
        const unsigned int* in32 = (l == 0) ? (const unsigned int*)hb
                                            : (const unsigned int*)z2b;
        float* bnRead = bnbuf[(l + 1) & 1];   // stats written by mlp(l-1)
        float* bnZero = bnbuf[l & 1];         // buffer mlp(l) will accumulate into
        k_agg<<<12500, 256, 0, stream>>>(in32, src_s, eattr_h,
                                         wek + l * 1024, eb + l * HID, row_ptr,
                                         bnRead, gam + (l ? (l - 1) * HID : 0),
                                         bet + (l ? (l - 1) * HID : 0),
                                         (l > 0) ? 1 : 0, bnZero, zb32);
        k_mlp<<<782, 256, 0, stream>>>((const unsigned short*)zb32,
                                       wp + (size_t)l * 16384, b1 + l * HID,
                                       wp + (size_t)(3 + l) * 16384, b2 + l * HID,
                                       z2b, bnZero);
    }

    // pool (fused last BN+ReLU; bn0 holds layer-2 stats) -> head
    k_pool<<<391, 128, 0, stream>>>(z2b, batch, bn0, gam + 2 * HID, bet + 2 * HID, g);
    k_head<<<1, 1024, 0, stream>>>(g, hW1, hb1, hW2, hb2, out);
}

// Round 11
// 614.148 us; speedup vs baseline: 1.0974x; 1.0974x over previous
//
#include <hip/hip_runtime.h>
#include <hip/hip_bf16.h>

// Problem constants (from reference)
#define N_NODES 50000
#define N_EDGES 640000
#define F_IN 64
#define EDGE_DIM 16
#define HID 128
#define N_LAYERS 3
#define NUM_GRAPHS 64
#define BN_EPS 1e-5f

typedef __attribute__((ext_vector_type(8))) short short8;    // 8 bf16 (4 VGPRs)
typedef __attribute__((ext_vector_type(4))) float f32x4;     // MFMA acc
typedef __attribute__((ext_vector_type(2))) __fp16 half2v;   // packed f16 pair (builtin type)

// bf16 <-> f32 helpers (manual, RNE on pack)
__device__ __forceinline__ float bfl(unsigned int u) {
    unsigned int v = u << 16; float f; __builtin_memcpy(&f, &v, 4); return f;
}
__device__ __forceinline__ float bfh(unsigned int u) {
    unsigned int v = u & 0xffff0000u; float f; __builtin_memcpy(&f, &v, 4); return f;
}
__device__ __forceinline__ unsigned int f2bf(float f) {
    unsigned int v; __builtin_memcpy(&v, &f, 4);
    v += 0x7fffu + ((v >> 16) & 1u);
    return v >> 16;
}
__device__ __forceinline__ unsigned int pack2(float lo, float hi) {
    return f2bf(lo) | (f2bf(hi) << 16);
}
__device__ __forceinline__ half2v u2h(unsigned int u) {
    half2v h; __builtin_memcpy(&h, &u, 4); return h;
}
__device__ __forceinline__ unsigned int pkh(float a, float b) {
    half2v h = __builtin_amdgcn_cvt_pkrtz(a, b);
    unsigned int u; __builtin_memcpy(&u, &h, 4); return u;
}

// ---------------------------------------------------------------------------
// CSR build (r9 pipeline — measured-good). row_ptr pre-zeroed by k_pack.
// ---------------------------------------------------------------------------
__global__ void k_hist(const int* __restrict__ dst, int* __restrict__ deg) {
    int e = blockIdx.x * 256 + threadIdx.x;   // grid exact: 2500*256 = 640000
    atomicAdd(&deg[dst[e]], 1);
}

__global__ void k_blockred(const int* __restrict__ deg, int* __restrict__ bsums) {
    __shared__ int s[256];
    int i = blockIdx.x * 256 + threadIdx.x;
    int v = (i < N_NODES) ? deg[i] : 0;
    s[threadIdx.x] = v;
    __syncthreads();
    for (int off = 128; off > 0; off >>= 1) {
        if (threadIdx.x < off) s[threadIdx.x] += s[threadIdx.x + off];
        __syncthreads();
    }
    if (threadIdx.x == 0) bsums[blockIdx.x] = s[0];
}

// parallel exclusive scan of block sums (nb <= 256, one block)
__global__ void k_scan_bsums(int* __restrict__ bsums, int nb) {
    __shared__ int s[256];
    const int tid = threadIdx.x;
    const int v = (tid < nb) ? bsums[tid] : 0;
    s[tid] = v;
    __syncthreads();
    for (int off = 1; off < 256; off <<= 1) {
        int t = 0;
        if (tid >= off) t = s[tid - off];
        __syncthreads();
        s[tid] += t;
        __syncthreads();
    }
    if (tid < nb) bsums[tid] = s[tid] - v;
}

__global__ void k_scan_blocks(int* __restrict__ deg_rowptr, const int* __restrict__ bsums,
                              int* __restrict__ cursor) {
    __shared__ int s[256];
    int tid = threadIdx.x;
    int i = blockIdx.x * 256 + tid;
    int v = (i < N_NODES) ? deg_rowptr[i] : 0;
    s[tid] = v;
    __syncthreads();
    for (int off = 1; off < 256; off <<= 1) {
        int t = 0;
        if (tid >= off) t = s[tid - off];
        __syncthreads();
        s[tid] += t;
        __syncthreads();
    }
    int excl = s[tid] - v + bsums[blockIdx.x];
    if (i < N_NODES) {
        deg_rowptr[i] = excl;
        cursor[i] = excl;
    }
    if (i == N_NODES - 1) deg_rowptr[N_NODES] = N_EDGES;
}

__global__ void k_fill(const int* __restrict__ dst, int* __restrict__ cursor,
                       int* __restrict__ elist) {
    int e = blockIdx.x * 256 + threadIdx.x;   // exact
    int p = atomicAdd(&cursor[dst[e]], 1);
    elist[p] = e;
}

// ---------------------------------------------------------------------------
// Edge materialization, 4 edges per thread (batched index->gather for MLP):
// src_s[p] = esrc[elist[p]]; eattr_h[p] = f16-pair packed eattr[elist[p]].
// ---------------------------------------------------------------------------
__global__ __launch_bounds__(256) void k_gather(const int* __restrict__ elist,
                                                const int* __restrict__ esrc,
                                                const float* __restrict__ eattr,
                                                int* __restrict__ src_s,
                                                uint4* __restrict__ eattr_h) {
    const int base = blockIdx.x * 1024;       // grid exact: 625*1024 = 640000
    const int tid = threadIdx.x;
    int p[4], eid[4];
#pragma unroll
    for (int j = 0; j < 4; ++j) p[j] = base + tid + j * 256;
#pragma unroll
    for (int j = 0; j < 4; ++j) eid[j] = elist[p[j]];
    int sv[4];
#pragma unroll
    for (int j = 0; j < 4; ++j) sv[j] = esrc[eid[j]];
    float4 a[4][4];
#pragma unroll
    for (int j = 0; j < 4; ++j) {
        const float* ep = eattr + (size_t)eid[j] * EDGE_DIM;
        a[j][0] = *(const float4*)ep;
        a[j][1] = *(const float4*)(ep + 4);
        a[j][2] = *(const float4*)(ep + 8);
        a[j][3] = *(const float4*)(ep + 12);
    }
#pragma unroll
    for (int j = 0; j < 4; ++j) {
        src_s[p[j]] = sv[j];
        eattr_h[p[j] * 2] = make_uint4(pkh(a[j][0].x, a[j][0].y), pkh(a[j][0].z, a[j][0].w),
                                       pkh(a[j][1].x, a[j][1].y), pkh(a[j][1].z, a[j][1].w));
        eattr_h[p[j] * 2 + 1] = make_uint4(pkh(a[j][2].x, a[j][2].y), pkh(a[j][2].z, a[j][2].w),
                                           pkh(a[j][3].x, a[j][3].y), pkh(a[j][3].z, a[j][3].w));
    }
}

// ---------------------------------------------------------------------------
// Merged weight packing + workspace zeroing:
// [0,12288) W1/W2 MFMA B-frags; [12288,13312) enc_W B-frags;
// [13312,16384) edge-weight f16 pairs; [16384,24576) zero g;
// [24576,74577) zero row_ptr.  Grid 292*256 = 74752.
// ---------------------------------------------------------------------------
__global__ void k_pack(const float* __restrict__ W1, const float* __restrict__ W2,
                       const float* __restrict__ encW, const float* __restrict__ eW,
                       unsigned short* __restrict__ wp, unsigned short* __restrict__ wpe,
                       unsigned int* __restrict__ wek, float* __restrict__ g,
                       int* __restrict__ row_ptr) {
    const int t = blockIdx.x * 256 + threadIdx.x;
    if (t < 12288) {
        const int mat = t >> 11;
        const int r = t & 2047;
        const int kstep = r >> 9;
        const int ntile = (r >> 6) & 7;
        const int lane = r & 63;
        const float* W = (mat < 3) ? (W1 + mat * 16384) : (W2 + (mat - 3) * 16384);
        const int kbase = kstep * 32 + ((lane >> 4) << 3);
        const int n = ntile * 16 + (lane & 15);
        unsigned int o[4];
#pragma unroll
        for (int jj = 0; jj < 4; ++jj)
            o[jj] = pack2(W[(kbase + 2 * jj) * HID + n], W[(kbase + 2 * jj + 1) * HID + n]);
        *(uint4*)(wp + (size_t)mat * 16384 + (((kstep << 3) + ntile) * 64 + lane) * 8) =
            make_uint4(o[0], o[1], o[2], o[3]);
    } else if (t < 13312) {
        const int r = t - 12288;
        const int kstep = r >> 9;
        const int ntile = (r >> 6) & 7;
        const int lane = r & 63;
        const int kbase = kstep * 32 + ((lane >> 4) << 3);
        const int n = ntile * 16 + (lane & 15);
        unsigned int o[4];
#pragma unroll
        for (int jj = 0; jj < 4; ++jj)
            o[jj] = pack2(encW[(kbase + 2 * jj) * HID + n], encW[(kbase + 2 * jj + 1) * HID + n]);
        *(uint4*)(wpe + (((kstep << 3) + ntile) * 64 + lane) * 8) =
            make_uint4(o[0], o[1], o[2], o[3]);
    } else if (t < 16384) {
        const int r = t - 13312;                    // 0..3071
        const int l = r >> 10;
        const int rr = r & 1023;
        const int kp = rr >> 7, f = rr & 127;
        const float a = eW[(l * EDGE_DIM + 2 * kp) * HID + f];
        const float b = eW[(l * EDGE_DIM + 2 * kp + 1) * HID + f];
        wek[r] = pkh(a, b);
    } else if (t < 24576) {
        g[t - 16384] = 0.f;
    } else if (t < 24576 + N_NODES + 1) {
        row_ptr[t - 24576] = 0;
    }
}

// ---------------------------------------------------------------------------
// Encoder via MFMA: hb = bf16(x @ enc_W + enc_b), reads fp32 x directly.
// ---------------------------------------------------------------------------
__global__ __launch_bounds__(256, 3) void k_encm(const float* __restrict__ x,
                                                 const unsigned short* __restrict__ wpe,
                                                 const float* __restrict__ b,
                                                 unsigned short* __restrict__ hb) {
    const int tid = threadIdx.x;
    const int w = tid >> 6, lane = tid & 63;
    const int q = lane >> 4, l15 = lane & 15;
    const int row0 = blockIdx.x * 64 + w * 16;
    const int ar = min(row0 + l15, N_NODES - 1);
    const float* xp = x + (size_t)ar * F_IN + q * 8;
    f32x4 acc[8];
#pragma unroll
    for (int nt = 0; nt < 8; ++nt) acc[nt] = (f32x4){0.f, 0.f, 0.f, 0.f};
#pragma unroll
    for (int ks = 0; ks < 2; ++ks) {
        const float4 v0 = *(const float4*)(xp + ks * 32);
        const float4 v1 = *(const float4*)(xp + ks * 32 + 4);
        unsigned int u[4] = {pack2(v0.x, v0.y), pack2(v0.z, v0.w),
                             pack2(v1.x, v1.y), pack2(v1.z, v1.w)};
        short8 a; __builtin_memcpy(&a, u, 16);
#pragma unroll
        for (int nt = 0; nt < 8; ++nt) {
            const short8 bf = *(const short8*)(wpe + (((ks << 3) + nt) * 64 + lane) * 8);
            acc[nt] = __builtin_amdgcn_mfma_f32_16x16x32_bf16(a, bf, acc[nt], 0, 0, 0);
        }
    }
    const int rowb = row0 + q * 4;
#pragma unroll
    for (int nt = 0; nt < 8; ++nt) {
        const float bias = b[nt * 16 + l15];
        const int cc = nt * 16 + l15;
#pragma unroll
        for (int reg = 0; reg < 4; ++reg) {
            const int r = rowb + reg;
            if (r < N_NODES)
                hb[(size_t)r * HID + cc] = (unsigned short)f2bf(acc[nt][reg] + bias);
        }
    }
}

// ---------------------------------------------------------------------------
// GINE aggregation (r9 body, measured-stable): one wave per node,
// fused BN+ReLU affine of the previous layer, f16 dot2 edge-MLP,
// chunk-of-4 with depth-2 gather pipeline pinned by sched_barrier(0).
// Block 0 additionally zeroes the NEXT BN accumulator (bnz).
// ---------------------------------------------------------------------------
__global__ __launch_bounds__(256, 2) void k_agg(const unsigned int* __restrict__ in32,
                                                const int* __restrict__ src_s,
                                                const uint4* __restrict__ eattr_h,
                                                const unsigned int* __restrict__ wek,
                                                const float* __restrict__ be,
                                                const int* __restrict__ row_ptr,
                                                const float* __restrict__ bnst,
                                                const float* __restrict__ gamma,
                                                const float* __restrict__ beta,
                                                const int bnmode,
                                                float* __restrict__ bnz,
                                                unsigned int* __restrict__ zb32) {
    if (blockIdx.x == 0) bnz[threadIdx.x] = 0.f;   // zero next-layer BN accum (256 floats)

    const int lane = threadIdx.x & 63;
    const int wv = threadIdx.x >> 6;
    const int f2 = lane * 2;
    half2v wx[8], wy[8];
#pragma unroll
    for (int j = 0; j < 8; ++j) {
        wx[j] = u2h(wek[j * 128 + f2]);
        wy[j] = u2h(wek[j * 128 + f2 + 1]);
    }
    const float2 eb = *(const float2*)&be[f2];

    // fused BN(prev layer)+ReLU affine
    float2 sc = make_float2(1.f, 1.f), sh = make_float2(0.f, 0.f);
    float rlo = -3.4e38f;
    if (bnmode) {
        const float invN = 1.0f / (float)N_NODES;
        const float m0 = bnst[f2] * invN, m1 = bnst[f2 + 1] * invN;
        const float v0 = fmaxf(bnst[128 + f2] * invN - m0 * m0, 0.f);
        const float v1 = fmaxf(bnst[128 + f2 + 1] * invN - m1 * m1, 0.f);
        const float r0 = rsqrtf(v0 + BN_EPS), r1 = rsqrtf(v1 + BN_EPS);
        sc = make_float2(gamma[f2] * r0, gamma[f2 + 1] * r1);
        sh = make_float2(fmaf(-m0, sc.x, beta[f2]), fmaf(-m1, sc.y, beta[f2 + 1]));
        rlo = 0.f;
    }

    const int n = blockIdx.x * 4 + wv;        // grid exact: 12500*4 = 50000
    const int base = __builtin_amdgcn_readfirstlane(row_ptr[n]);
    const int deg = __builtin_amdgcn_readfirstlane(row_ptr[n + 1]) - base;

    const unsigned int uself = in32[n * 64 + lane];
    float2 acc = make_float2(fmaxf(fmaf(bfl(uself), sc.x, sh.x), rlo),
                             fmaxf(fmaf(bfh(uself), sc.y, sh.y), rlo));

    if (deg > 0) {
        const int* sp = src_s + base;
        const uint4* ep = eattr_h + (size_t)base * 2;
        const int last = deg - 1;
        const int nch = (deg + 3) >> 2;

        unsigned int huC[4], huN[4];
        uint4 eaC[4][2], eaN[4][2];
        int s2[4];
        {
            int s0[4], s1[4];
#pragma unroll
            for (int j = 0; j < 4; ++j) s0[j] = sp[min(j, last)];
#pragma unroll
            for (int j = 0; j < 4; ++j) huC[j] = in32[s0[j] * 64 + lane];
#pragma unroll
            for (int j = 0; j < 4; ++j) s1[j] = sp[min(4 + j, last)];
            if (nch > 1) {
#pragma unroll
                for (int j = 0; j < 4; ++j) huN[j] = in32[s1[j] * 64 + lane];
            } else {
#pragma unroll
                for (int j = 0; j < 4; ++j) huN[j] = 0u;
            }
#pragma unroll
            for (int j = 0; j < 4; ++j) {
                const int e = min(j, last);
                eaC[j][0] = ep[e * 2]; eaC[j][1] = ep[e * 2 + 1];
            }
#pragma unroll
            for (int j = 0; j < 4; ++j) s2[j] = sp[min(8 + j, last)];
        }
        for (int c = 0; c < nch; ++c) {
            // ---- issue section: gathers for c+2, srcs for c+3, attrs c+1 ----
            unsigned int huNN[4] = {0u, 0u, 0u, 0u};
            if (c + 2 < nch) {
#pragma unroll
                for (int j = 0; j < 4; ++j) huNN[j] = in32[s2[j] * 64 + lane];
            }
            int s3[4];
#pragma unroll
            for (int j = 0; j < 4; ++j) s3[j] = sp[min((c + 3) * 4 + j, last)];
            if (c + 1 < nch) {
#pragma unroll
                for (int j = 0; j < 4; ++j) {
                    const int e = min((c + 1) * 4 + j, last);
                    eaN[j][0] = ep[e * 2]; eaN[j][1] = ep[e * 2 + 1];
                }
            }
            // pin: keep the issue section ABOVE the compute section
            __builtin_amdgcn_sched_barrier(0);
            // ---- compute chunk c ----
            const int rem = deg - c * 4;
#pragma unroll
            for (int j = 0; j < 4; ++j) {
                if (j < rem) {
                    const unsigned int* au = (const unsigned int*)&eaC[j][0];
                    float ex = eb.x, ey = eb.y;
#pragma unroll
                    for (int k = 0; k < 8; ++k) {
                        const half2v a = u2h(au[k]);
                        ex = __builtin_amdgcn_fdot2(a, wx[k], ex, false);
                        ey = __builtin_amdgcn_fdot2(a, wy[k], ey, false);
                    }
                    const float hx = fmaxf(fmaf(bfl(huC[j]), sc.x, sh.x), rlo);
                    const float hy = fmaxf(fmaf(bfh(huC[j]), sc.y, sh.y), rlo);
                    acc.x += fmaxf(hx + ex, 0.f);
                    acc.y += fmaxf(hy + ey, 0.f);
                }
            }
            // rotate pipeline
            if (c + 1 < nch) {
#pragma unroll
                for (int j = 0; j < 4; ++j) {
                    huC[j] = huN[j]; huN[j] = huNN[j];
                    eaC[j][0] = eaN[j][0]; eaC[j][1] = eaN[j][1];
                    s2[j] = s3[j];
                }
            }
        }
    }
    zb32[n * 64 + lane] = pack2(acc.x, acc.y);
}

// ---------------------------------------------------------------------------
// Fused node MLP via bf16 MFMA (16x16x32): z2b = bf16(relu(z@W1+b1)@W2+b2),
// plus BN sum/sumsq partials (fp32, from accumulators).
// ---------------------------------------------------------------------------
#define Z1LD 136

__global__ __launch_bounds__(256, 3) void k_mlp(const unsigned short* __restrict__ zb,
                                                const unsigned short* __restrict__ w1p,
                                                const float* __restrict__ b1,
                                                const unsigned short* __restrict__ w2p,
                                                const float* __restrict__ b2,
                                                unsigned short* __restrict__ z2b,
                                                float* __restrict__ bn) {
    __shared__ unsigned short z1s[64 * Z1LD];
    __shared__ float redA[512];
    __shared__ float redB[512];
    const int tid = threadIdx.x;
    const int w = tid >> 6, lane = tid & 63;
    const int q = lane >> 4, l15 = lane & 15;
    const int row0 = blockIdx.x * 64 + w * 16;

    const int ar = min(row0 + l15, N_NODES - 1);
    const unsigned short* aptr = zb + (size_t)ar * HID + q * 8;

    f32x4 acc[8];
#pragma unroll
    for (int nt = 0; nt < 8; ++nt) acc[nt] = (f32x4){0.f, 0.f, 0.f, 0.f};

#pragma unroll
    for (int ks = 0; ks < 4; ++ks) {
        const short8 a = *(const short8*)(aptr + ks * 32);
#pragma unroll
        for (int nt = 0; nt < 8; ++nt) {
            const short8 b = *(const short8*)(w1p + (((ks << 3) + nt) * 64 + lane) * 8);
            acc[nt] = __builtin_amdgcn_mfma_f32_16x16x32_bf16(a, b, acc[nt], 0, 0, 0);
        }
    }
    {
        const int lr0 = w * 16 + q * 4;
#pragma unroll
        for (int nt = 0; nt < 8; ++nt) {
            const float bias = b1[nt * 16 + l15];
            const int cc = nt * 16 + l15;
#pragma unroll
            for (int reg = 0; reg < 4; ++reg) {
                const float v = fmaxf(acc[nt][reg] + bias, 0.f);
                z1s[(lr0 + reg) * Z1LD + cc] = (unsigned short)f2bf(v);
            }
        }
    }
#pragma unroll
    for (int nt = 0; nt < 8; ++nt) acc[nt] = (f32x4){0.f, 0.f, 0.f, 0.f};
    const unsigned short* a2p = &z1s[(w * 16 + l15) * Z1LD + q * 8];
#pragma unroll
    for (int ks = 0; ks < 4; ++ks) {
        const short8 a = *(const short8*)(a2p + ks * 32);
#pragma unroll
        for (int nt = 0; nt < 8; ++nt) {
            const short8 b = *(const short8*)(w2p + (((ks << 3) + nt) * 64 + lane) * 8);
            acc[nt] = __builtin_amdgcn_mfma_f32_16x16x32_bf16(a, b, acc[nt], 0, 0, 0);
        }
    }
    float s[8], sq[8];
    const int rowb = row0 + q * 4;
#pragma unroll
    for (int nt = 0; nt < 8; ++nt) {
        const float bias = b2[nt * 16 + l15];
        const int cc = nt * 16 + l15;
        float ls = 0.f, lq = 0.f;
#pragma unroll
        for (int reg = 0; reg < 4; ++reg) {
            const int r = rowb + reg;
            const float v = acc[nt][reg] + bias;
            if (r < N_NODES) {
                z2b[(size_t)r * HID + cc] = (unsigned short)f2bf(v);
                ls += v;
                lq = fmaf(v, v, lq);
            }
        }
        s[nt] = ls; sq[nt] = lq;
    }
#pragma unroll
    for (int nt = 0; nt < 8; ++nt) {
        s[nt] += __shfl_xor(s[nt], 16, 64);
        s[nt] += __shfl_xor(s[nt], 32, 64);
        sq[nt] += __shfl_xor(sq[nt], 16, 64);
        sq[nt] += __shfl_xor(sq[nt], 32, 64);
    }
    if (lane < 16) {
#pragma unroll
        for (int nt = 0; nt < 8; ++nt) {
            redA[w * 128 + nt * 16 + lane] = s[nt];
            redB[w * 128 + nt * 16 + lane] = sq[nt];
        }
    }
    __syncthreads();
    if (tid < 128) {
        float t = redA[tid] + redA[128 + tid] + redA[256 + tid] + redA[384 + tid];
        atomicAdd(&bn[tid], t);
    } else {
        const int c = tid - 128;
        float t = redB[c] + redB[128 + c] + redB[256 + c] + redB[384 + c];
        atomicAdd(&bn[128 + c], t);
    }
}

// ---------------------------------------------------------------------------
// Global add pool (batch sorted), with fused BN+ReLU of the last layer.
// ---------------------------------------------------------------------------
__global__ void k_pool(const unsigned short* __restrict__ z2b, const int* __restrict__ batch,
                       const float* __restrict__ bnst, const float* __restrict__ gamma,
                       const float* __restrict__ beta, float* __restrict__ g) {
    const int f = threadIdx.x;            // 128 threads
    const float invN = 1.0f / (float)N_NODES;
    const float m = bnst[f] * invN;
    const float var = fmaxf(bnst[128 + f] * invN - m * m, 0.f);
    const float r = rsqrtf(var + BN_EPS);
    const float sc = gamma[f] * r;
    const float sh = fmaf(-m, sc, beta[f]);

    const int n0 = blockIdx.x * 128;
    const int nend = min(n0 + 128, N_NODES);
    float acc = 0.f;
    int cur = batch[n0];
    for (int n = n0; n < nend; ++n) {
        const int bb = batch[n];
        if (bb != cur) {
            atomicAdd(&g[cur * HID + f], acc);
            acc = 0.f;
            cur = bb;
        }
        const float raw = bfl((unsigned int)z2b[n * HID + f]);
        acc += fmaxf(fmaf(raw, sc, sh), 0.f);
    }
    atomicAdd(&g[cur * HID + f], acc);
}

// ---------------------------------------------------------------------------
// Head: out = relu(g @ hW1 + hb1) @ hW2 + hb2, single block of 1024.
// ---------------------------------------------------------------------------
__global__ __launch_bounds__(1024) void k_head(const float* __restrict__ g,
                                               const float* __restrict__ W1h,
                                               const float* __restrict__ b1h,
                                               const float* __restrict__ W2h,
                                               const float* __restrict__ b2h,
                                               float* __restrict__ out) {
    __shared__ float g1s[NUM_GRAPHS * HID];
    const int tid = threadIdx.x;
#pragma unroll
    for (int i = 0; i < 8; ++i) {
        const int idx = i * 1024 + tid;       // 8192 outputs
        const int r = idx >> 7, c = idx & 127;
        float acc = b1h[c];
        for (int k = 0; k < 128; ++k) acc = fmaf(g[r * HID + k], W1h[k * HID + c], acc);
        g1s[idx] = fmaxf(acc, 0.f);
    }
    __syncthreads();
    if (tid < NUM_GRAPHS * 2) {
        const int r = tid >> 1, c = tid & 1;
        float acc = b2h[c];
        for (int k = 0; k < 128; ++k) acc = fmaf(g1s[r * HID + k], W2h[k * 2 + c], acc);
        out[tid] = acc;
    }
}

// ---------------------------------------------------------------------------
// Launch — 15 dispatches
// ---------------------------------------------------------------------------
extern "C" void kernel_launch(void* const* d_in, const int* in_sizes, int n_in,
                              void* d_out, int out_size, void* d_ws, size_t ws_size,
                              hipStream_t stream) {
    const float* x     = (const float*)d_in[0];
    const int*   ei    = (const int*)d_in[1];
    const float* eattr = (const float*)d_in[2];
    const int*   batch = (const int*)d_in[3];
    const float* encW  = (const float*)d_in[4];
    const float* encb  = (const float*)d_in[5];
    const float* eW    = (const float*)d_in[6];
    const float* eb    = (const float*)d_in[7];
    const float* W1    = (const float*)d_in[8];
    const float* b1    = (const float*)d_in[9];
    const float* W2    = (const float*)d_in[10];
    const float* b2    = (const float*)d_in[11];
    const float* gam   = (const float*)d_in[12];
    const float* bet   = (const float*)d_in[13];
    const float* hW1   = (const float*)d_in[14];
    const float* hb1   = (const float*)d_in[15];
    const float* hW2   = (const float*)d_in[16];
    const float* hb2   = (const float*)d_in[17];
    float* out = (float*)d_out;

    // workspace layout (float-sized slots)
    float* ws = (float*)d_ws;
    unsigned short* z2b = (unsigned short*)ws;              // 6.4M u16 = 3.2M floats
    float* bn0 = ws + 3200000;              // 256
    float* bn1 = ws + 3200256;              // 256
    float* g   = ws + 3200512;              // 8,192
    unsigned short* hb = (unsigned short*)(ws + 3216640);   // 6.4M u16
    unsigned int* zb32 = (unsigned int*)(ws + 6416640);     // 6.4M u16
    int* row_ptr = (int*)(ws + 11216640);   // 50,001
    int* cursor  = row_ptr + N_NODES + 1;   // 50,000
    int* elist   = cursor + N_NODES;        // 640,000
    int* bsums   = elist + N_EDGES;         // 256
    int* src_s   = bsums + 256;             // 640,000
    uint4* eattr_h = (uint4*)(ws + 12596900);               // 5.12M u32
    unsigned short* wp  = (unsigned short*)(ws + 17716900); // 98,304 u16
    unsigned short* wpe = (unsigned short*)(ws + 17766100); // 8,192 u16
    unsigned int*   wek = (unsigned int*)(ws + 17770200);   // 3,072 u32

    const int* esrc = ei;
    const int* edst = ei + N_EDGES;

    // pack weights + zero row_ptr/g (replaces 2 memsets)
    k_pack<<<292, 256, 0, stream>>>(W1, W2, encW, eW, wp, wpe, wek, g, row_ptr);
    // CSR build (r9 pipeline): hist -> hierarchical scan -> fill -> gather
    k_hist<<<N_EDGES / 256, 256, 0, stream>>>(edst, row_ptr);
    k_blockred<<<196, 256, 0, stream>>>(row_ptr, bsums);
    k_scan_bsums<<<1, 256, 0, stream>>>(bsums, 196);
    k_scan_blocks<<<196, 256, 0, stream>>>(row_ptr, bsums, cursor);
    k_fill<<<N_EDGES / 256, 256, 0, stream>>>(edst, cursor, elist);
    k_gather<<<N_EDGES / 1024, 256, 0, stream>>>(elist, esrc, eattr, src_s, eattr_h);

    // encoder -> bf16 h (MFMA, reads fp32 x directly)
    k_encm<<<782, 256, 0, stream>>>(x, wpe, encb, hb);

    // per layer: agg (fused prev-BN+ReLU, zeroes next bn buffer) -> mlp
    float* bnbuf[2] = {bn0, bn1};
    for (int l = 0; l < N_LAYERS; ++l) {
        const unsigned int* in32 = (l == 0) ? (const unsigned int*)hb
                                            : (const unsigned int*)z2b;
        float* bnRead = bnbuf[(l + 1) & 1];   // stats written by mlp(l-1)
        float* bnZero = bnbuf[l & 1];         // buffer mlp(l) will accumulate into
        k_agg<<<12500, 256, 0, stream>>>(in32, src_s, eattr_h,
                                         wek + l * 1024, eb + l * HID, row_ptr,
                                         bnRead, gam + (l ? (l - 1) * HID : 0),
                                         bet + (l ? (l - 1) * HID : 0),
                                         (l > 0) ? 1 : 0, bnZero, zb32);
        k_mlp<<<782, 256, 0, stream>>>((const unsigned short*)zb32,
                                       wp + (size_t)l * 16384, b1 + l * HID,
                                       wp + (size_t)(3 + l) * 16384, b2 + l * HID,
                                       z2b, bnZero);
    }

    // pool (fused last BN+ReLU; bn0 holds layer-2 stats) -> head
    k_pool<<<391, 128, 0, stream>>>(z2b, batch, bn0, gam + 2 * HID, bet + 2 * HID, g);
    k_head<<<1, 1024, 0, stream>>>(g, hW1, hb1, hW2, hb2, out);
}

// Round 12
// 578.120 us; speedup vs baseline: 1.1658x; 1.0623x over previous
//
#include <hip/hip_runtime.h>
#include <hip/hip_bf16.h>

// Problem constants (from reference)
#define N_NODES 50000
#define N_EDGES 640000
#define F_IN 64
#define EDGE_DIM 16
#define HID 128
#define N_LAYERS 3
#define NUM_GRAPHS 64
#define BN_EPS 1e-5f

typedef __attribute__((ext_vector_type(8))) short short8;    // 8 bf16 (4 VGPRs)
typedef __attribute__((ext_vector_type(4))) float f32x4;     // MFMA acc
typedef __attribute__((ext_vector_type(2))) __fp16 half2v;   // packed f16 pair (builtin type)

// bf16 <-> f32 helpers (manual, RNE on pack)
__device__ __forceinline__ float bfl(unsigned int u) {
    unsigned int v = u << 16; float f; __builtin_memcpy(&f, &v, 4); return f;
}
__device__ __forceinline__ float bfh(unsigned int u) {
    unsigned int v = u & 0xffff0000u; float f; __builtin_memcpy(&f, &v, 4); return f;
}
__device__ __forceinline__ unsigned int f2bf(float f) {
    unsigned int v; __builtin_memcpy(&v, &f, 4);
    v += 0x7fffu + ((v >> 16) & 1u);
    return v >> 16;
}
__device__ __forceinline__ unsigned int pack2(float lo, float hi) {
    return f2bf(lo) | (f2bf(hi) << 16);
}
__device__ __forceinline__ half2v u2h(unsigned int u) {
    half2v h; __builtin_memcpy(&h, &u, 4); return h;
}
__device__ __forceinline__ unsigned int pkh(float a, float b) {
    half2v h = __builtin_amdgcn_cvt_pkrtz(a, b);
    unsigned int u; __builtin_memcpy(&u, &h, 4); return u;
}

// ---------------------------------------------------------------------------
// CSR build. row_ptr pre-zeroed by k_pack.
// ---------------------------------------------------------------------------
__global__ void k_hist(const int* __restrict__ dst, int* __restrict__ deg) {
    int e = blockIdx.x * 256 + threadIdx.x;   // grid exact: 2500*256 = 640000
    atomicAdd(&deg[dst[e]], 1);
}

__global__ void k_blockred(const int* __restrict__ deg, int* __restrict__ bsums) {
    __shared__ int s[256];
    int i = blockIdx.x * 256 + threadIdx.x;
    int v = (i < N_NODES) ? deg[i] : 0;
    s[threadIdx.x] = v;
    __syncthreads();
    for (int off = 128; off > 0; off >>= 1) {
        if (threadIdx.x < off) s[threadIdx.x] += s[threadIdx.x + off];
        __syncthreads();
    }
    if (threadIdx.x == 0) bsums[blockIdx.x] = s[0];
}

// parallel exclusive scan of block sums (nb <= 256, one block)
__global__ void k_scan_bsums(int* __restrict__ bsums, int nb) {
    __shared__ int s[256];
    const int tid = threadIdx.x;
    const int v = (tid < nb) ? bsums[tid] : 0;
    s[tid] = v;
    __syncthreads();
    for (int off = 1; off < 256; off <<= 1) {
        int t = 0;
        if (tid >= off) t = s[tid - off];
        __syncthreads();
        s[tid] += t;
        __syncthreads();
    }
    if (tid < nb) bsums[tid] = s[tid] - v;
}

__global__ void k_scan_blocks(int* __restrict__ deg_rowptr, const int* __restrict__ bsums,
                              int* __restrict__ cursor) {
    __shared__ int s[256];
    int tid = threadIdx.x;
    int i = blockIdx.x * 256 + tid;
    int v = (i < N_NODES) ? deg_rowptr[i] : 0;
    s[tid] = v;
    __syncthreads();
    for (int off = 1; off < 256; off <<= 1) {
        int t = 0;
        if (tid >= off) t = s[tid - off];
        __syncthreads();
        s[tid] += t;
        __syncthreads();
    }
    int excl = s[tid] - v + bsums[blockIdx.x];
    if (i < N_NODES) {
        deg_rowptr[i] = excl;
        cursor[i] = excl;
    }
    if (i == N_NODES - 1) deg_rowptr[N_NODES] = N_EDGES;
}

// ---------------------------------------------------------------------------
// Fused fill + materialize (r10 component, exonerated): for each original
// edge e (coalesced reads), claim CSR slot p = cursor[dst]++ and
// scatter-write src_s[p] + f16-pair packed eattr. No elist, no random reads.
// ---------------------------------------------------------------------------
__global__ __launch_bounds__(256) void k_fillg(const int* __restrict__ esrc,
                                               const int* __restrict__ edst,
                                               const float* __restrict__ eattr,
                                               int* __restrict__ cursor,
                                               int* __restrict__ src_s,
                                               uint4* __restrict__ eattr_h) {
    const int e = blockIdx.x * 256 + threadIdx.x;   // exact: 2500*256
    const int d = edst[e];
    const int sv = esrc[e];
    const float* ep = eattr + (size_t)e * EDGE_DIM;
    const float4 a0 = *(const float4*)ep;
    const float4 a1 = *(const float4*)(ep + 4);
    const float4 a2 = *(const float4*)(ep + 8);
    const float4 a3 = *(const float4*)(ep + 12);
    const int p = atomicAdd(&cursor[d], 1);
    src_s[p] = sv;
    eattr_h[p * 2] = make_uint4(pkh(a0.x, a0.y), pkh(a0.z, a0.w),
                                pkh(a1.x, a1.y), pkh(a1.z, a1.w));
    eattr_h[p * 2 + 1] = make_uint4(pkh(a2.x, a2.y), pkh(a2.z, a2.w),
                                    pkh(a3.x, a3.y), pkh(a3.z, a3.w));
}

// ---------------------------------------------------------------------------
// Merged weight packing + workspace zeroing:
// [0,12288) W1/W2 MFMA B-frags; [12288,13312) enc_W B-frags;
// [13312,16384) edge-weight f16 pairs; [16384,24576) zero g;
// [24576,74577) zero row_ptr.  Grid 292*256 = 74752.
// ---------------------------------------------------------------------------
__global__ void k_pack(const float* __restrict__ W1, const float* __restrict__ W2,
                       const float* __restrict__ encW, const float* __restrict__ eW,
                       unsigned short* __restrict__ wp, unsigned short* __restrict__ wpe,
                       unsigned int* __restrict__ wek, float* __restrict__ g,
                       int* __restrict__ row_ptr) {
    const int t = blockIdx.x * 256 + threadIdx.x;
    if (t < 12288) {
        const int mat = t >> 11;
        const int r = t & 2047;
        const int kstep = r >> 9;
        const int ntile = (r >> 6) & 7;
        const int lane = r & 63;
        const float* W = (mat < 3) ? (W1 + mat * 16384) : (W2 + (mat - 3) * 16384);
        const int kbase = kstep * 32 + ((lane >> 4) << 3);
        const int n = ntile * 16 + (lane & 15);
        unsigned int o[4];
#pragma unroll
        for (int jj = 0; jj < 4; ++jj)
            o[jj] = pack2(W[(kbase + 2 * jj) * HID + n], W[(kbase + 2 * jj + 1) * HID + n]);
        *(uint4*)(wp + (size_t)mat * 16384 + (((kstep << 3) + ntile) * 64 + lane) * 8) =
            make_uint4(o[0], o[1], o[2], o[3]);
    } else if (t < 13312) {
        const int r = t - 12288;
        const int kstep = r >> 9;
        const int ntile = (r >> 6) & 7;
        const int lane = r & 63;
        const int kbase = kstep * 32 + ((lane >> 4) << 3);
        const int n = ntile * 16 + (lane & 15);
        unsigned int o[4];
#pragma unroll
        for (int jj = 0; jj < 4; ++jj)
            o[jj] = pack2(encW[(kbase + 2 * jj) * HID + n], encW[(kbase + 2 * jj + 1) * HID + n]);
        *(uint4*)(wpe + (((kstep << 3) + ntile) * 64 + lane) * 8) =
            make_uint4(o[0], o[1], o[2], o[3]);
    } else if (t < 16384) {
        const int r = t - 13312;                    // 0..3071
        const int l = r >> 10;
        const int rr = r & 1023;
        const int kp = rr >> 7, f = rr & 127;
        const float a = eW[(l * EDGE_DIM + 2 * kp) * HID + f];
        const float b = eW[(l * EDGE_DIM + 2 * kp + 1) * HID + f];
        wek[r] = pkh(a, b);
    } else if (t < 24576) {
        g[t - 16384] = 0.f;
    } else if (t < 24576 + N_NODES + 1) {
        row_ptr[t - 24576] = 0;
    }
}

// ---------------------------------------------------------------------------
// Encoder via MFMA: hb = bf16(x @ enc_W + enc_b), reads fp32 x directly.
// ---------------------------------------------------------------------------
__global__ __launch_bounds__(256, 3) void k_encm(const float* __restrict__ x,
                                                 const unsigned short* __restrict__ wpe,
                                                 const float* __restrict__ b,
                                                 unsigned short* __restrict__ hb) {
    const int tid = threadIdx.x;
    const int w = tid >> 6, lane = tid & 63;
    const int q = lane >> 4, l15 = lane & 15;
    const int row0 = blockIdx.x * 64 + w * 16;
    const int ar = min(row0 + l15, N_NODES - 1);
    const float* xp = x + (size_t)ar * F_IN + q * 8;
    f32x4 acc[8];
#pragma unroll
    for (int nt = 0; nt < 8; ++nt) acc[nt] = (f32x4){0.f, 0.f, 0.f, 0.f};
#pragma unroll
    for (int ks = 0; ks < 2; ++ks) {
        const float4 v0 = *(const float4*)(xp + ks * 32);
        const float4 v1 = *(const float4*)(xp + ks * 32 + 4);
        unsigned int u[4] = {pack2(v0.x, v0.y), pack2(v0.z, v0.w),
                             pack2(v1.x, v1.y), pack2(v1.z, v1.w)};
        short8 a; __builtin_memcpy(&a, u, 16);
#pragma unroll
        for (int nt = 0; nt < 8; ++nt) {
            const short8 bf = *(const short8*)(wpe + (((ks << 3) + nt) * 64 + lane) * 8);
            acc[nt] = __builtin_amdgcn_mfma_f32_16x16x32_bf16(a, bf, acc[nt], 0, 0, 0);
        }
    }
    const int rowb = row0 + q * 4;
#pragma unroll
    for (int nt = 0; nt < 8; ++nt) {
        const float bias = b[nt * 16 + l15];
        const int cc = nt * 16 + l15;
#pragma unroll
        for (int reg = 0; reg < 4; ++reg) {
            const int r = rowb + reg;
            if (r < N_NODES)
                hb[(size_t)r * HID + cc] = (unsigned short)f2bf(acc[nt][reg] + bias);
        }
    }
}

// ---------------------------------------------------------------------------
// GINE aggregation: one wave per node, fused BN+ReLU affine of the previous
// layer, f16 dot2 edge-MLP, chunk-of-4 with depth-2 gather pipeline.
// NO sched_barrier this round (testing the m141 pin-hurts hypothesis).
// Block 0 additionally zeroes the NEXT BN accumulator (bnz).
// ---------------------------------------------------------------------------
__global__ __launch_bounds__(256, 2) void k_agg(const unsigned int* __restrict__ in32,
                                                const int* __restrict__ src_s,
                                                const uint4* __restrict__ eattr_h,
                                                const unsigned int* __restrict__ wek,
                                                const float* __restrict__ be,
                                                const int* __restrict__ row_ptr,
                                                const float* __restrict__ bnst,
                                                const float* __restrict__ gamma,
                                                const float* __restrict__ beta,
                                                const int bnmode,
                                                float* __restrict__ bnz,
                                                unsigned int* __restrict__ zb32) {
    if (blockIdx.x == 0) bnz[threadIdx.x] = 0.f;   // zero next-layer BN accum (256 floats)

    const int lane = threadIdx.x & 63;
    const int wv = threadIdx.x >> 6;
    const int f2 = lane * 2;
    half2v wx[8], wy[8];
#pragma unroll
    for (int j = 0; j < 8; ++j) {
        wx[j] = u2h(wek[j * 128 + f2]);
        wy[j] = u2h(wek[j * 128 + f2 + 1]);
    }
    const float2 eb = *(const float2*)&be[f2];

    // fused BN(prev layer)+ReLU affine
    float2 sc = make_float2(1.f, 1.f), sh = make_float2(0.f, 0.f);
    float rlo = -3.4e38f;
    if (bnmode) {
        const float invN = 1.0f / (float)N_NODES;
        const float m0 = bnst[f2] * invN, m1 = bnst[f2 + 1] * invN;
        const float v0 = fmaxf(bnst[128 + f2] * invN - m0 * m0, 0.f);
        const float v1 = fmaxf(bnst[128 + f2 + 1] * invN - m1 * m1, 0.f);
        const float r0 = rsqrtf(v0 + BN_EPS), r1 = rsqrtf(v1 + BN_EPS);
        sc = make_float2(gamma[f2] * r0, gamma[f2 + 1] * r1);
        sh = make_float2(fmaf(-m0, sc.x, beta[f2]), fmaf(-m1, sc.y, beta[f2 + 1]));
        rlo = 0.f;
    }

    const int n = blockIdx.x * 4 + wv;        // grid exact: 12500*4 = 50000
    const int base = __builtin_amdgcn_readfirstlane(row_ptr[n]);
    const int deg = __builtin_amdgcn_readfirstlane(row_ptr[n + 1]) - base;

    const unsigned int uself = in32[n * 64 + lane];
    float2 acc = make_float2(fmaxf(fmaf(bfl(uself), sc.x, sh.x), rlo),
                             fmaxf(fmaf(bfh(uself), sc.y, sh.y), rlo));

    if (deg > 0) {
        const int* sp = src_s + base;
        const uint4* ep = eattr_h + (size_t)base * 2;
        const int last = deg - 1;
        const int nch = (deg + 3) >> 2;

        unsigned int huC[4], huN[4];
        uint4 eaC[4][2], eaN[4][2];
        int s2[4];
        {
            int s0[4], s1[4];
#pragma unroll
            for (int j = 0; j < 4; ++j) s0[j] = sp[min(j, last)];
#pragma unroll
            for (int j = 0; j < 4; ++j) huC[j] = in32[s0[j] * 64 + lane];
#pragma unroll
            for (int j = 0; j < 4; ++j) s1[j] = sp[min(4 + j, last)];
            if (nch > 1) {
#pragma unroll
                for (int j = 0; j < 4; ++j) huN[j] = in32[s1[j] * 64 + lane];
            } else {
#pragma unroll
                for (int j = 0; j < 4; ++j) huN[j] = 0u;
            }
#pragma unroll
            for (int j = 0; j < 4; ++j) {
                const int e = min(j, last);
                eaC[j][0] = ep[e * 2]; eaC[j][1] = ep[e * 2 + 1];
            }
#pragma unroll
            for (int j = 0; j < 4; ++j) s2[j] = sp[min(8 + j, last)];
        }
        for (int c = 0; c < nch; ++c) {
            // ---- issue section: gathers for c+2, srcs for c+3, attrs c+1 ----
            unsigned int huNN[4] = {0u, 0u, 0u, 0u};
            if (c + 2 < nch) {
#pragma unroll
                for (int j = 0; j < 4; ++j) huNN[j] = in32[s2[j] * 64 + lane];
            }
            int s3[4];
#pragma unroll
            for (int j = 0; j < 4; ++j) s3[j] = sp[min((c + 3) * 4 + j, last)];
            if (c + 1 < nch) {
#pragma unroll
                for (int j = 0; j < 4; ++j) {
                    const int e = min((c + 1) * 4 + j, last);
                    eaN[j][0] = ep[e * 2]; eaN[j][1] = ep[e * 2 + 1];
                }
            }
            // ---- compute chunk c ----
            const int rem = deg - c * 4;
#pragma unroll
            for (int j = 0; j < 4; ++j) {
                if (j < rem) {
                    const unsigned int* au = (const unsigned int*)&eaC[j][0];
                    float ex = eb.x, ey = eb.y;
#pragma unroll
                    for (int k = 0; k < 8; ++k) {
                        const half2v a = u2h(au[k]);
                        ex = __builtin_amdgcn_fdot2(a, wx[k], ex, false);
                        ey = __builtin_amdgcn_fdot2(a, wy[k], ey, false);
                    }
                    const float hx = fmaxf(fmaf(bfl(huC[j]), sc.x, sh.x), rlo);
                    const float hy = fmaxf(fmaf(bfh(huC[j]), sc.y, sh.y), rlo);
                    acc.x += fmaxf(hx + ex, 0.f);
                    acc.y += fmaxf(hy + ey, 0.f);
                }
            }
            // rotate pipeline
            if (c + 1 < nch) {
#pragma unroll
                for (int j = 0; j < 4; ++j) {
                    huC[j] = huN[j]; huN[j] = huNN[j];
                    eaC[j][0] = eaN[j][0]; eaC[j][1] = eaN[j][1];
                    s2[j] = s3[j];
                }
            }
        }
    }
    zb32[n * 64 + lane] = pack2(acc.x, acc.y);
}

// ---------------------------------------------------------------------------
// Fused node MLP via bf16 MFMA (16x16x32): z2b = bf16(relu(z@W1+b1)@W2+b2),
// plus BN sum/sumsq partials (fp32, from accumulators).
// ---------------------------------------------------------------------------
#define Z1LD 136

__global__ __launch_bounds__(256, 3) void k_mlp(const unsigned short* __restrict__ zb,
                                                const unsigned short* __restrict__ w1p,
                                                const float* __restrict__ b1,
                                                const unsigned short* __restrict__ w2p,
                                                const float* __restrict__ b2,
                                                unsigned short* __restrict__ z2b,
                                                float* __restrict__ bn) {
    __shared__ unsigned short z1s[64 * Z1LD];
    __shared__ float redA[512];
    __shared__ float redB[512];
    const int tid = threadIdx.x;
    const int w = tid >> 6, lane = tid & 63;
    const int q = lane >> 4, l15 = lane & 15;
    const int row0 = blockIdx.x * 64 + w * 16;

    const int ar = min(row0 + l15, N_NODES - 1);
    const unsigned short* aptr = zb + (size_t)ar * HID + q * 8;

    f32x4 acc[8];
#pragma unroll
    for (int nt = 0; nt < 8; ++nt) acc[nt] = (f32x4){0.f, 0.f, 0.f, 0.f};

#pragma unroll
    for (int ks = 0; ks < 4; ++ks) {
        const short8 a = *(const short8*)(aptr + ks * 32);
#pragma unroll
        for (int nt = 0; nt < 8; ++nt) {
            const short8 b = *(const short8*)(w1p + (((ks << 3) + nt) * 64 + lane) * 8);
            acc[nt] = __builtin_amdgcn_mfma_f32_16x16x32_bf16(a, b, acc[nt], 0, 0, 0);
        }
    }
    {
        const int lr0 = w * 16 + q * 4;
#pragma unroll
        for (int nt = 0; nt < 8; ++nt) {
            const float bias = b1[nt * 16 + l15];
            const int cc = nt * 16 + l15;
#pragma unroll
            for (int reg = 0; reg < 4; ++reg) {
                const float v = fmaxf(acc[nt][reg] + bias, 0.f);
                z1s[(lr0 + reg) * Z1LD + cc] = (unsigned short)f2bf(v);
            }
        }
    }
#pragma unroll
    for (int nt = 0; nt < 8; ++nt) acc[nt] = (f32x4){0.f, 0.f, 0.f, 0.f};
    const unsigned short* a2p = &z1s[(w * 16 + l15) * Z1LD + q * 8];
#pragma unroll
    for (int ks = 0; ks < 4; ++ks) {
        const short8 a = *(const short8*)(a2p + ks * 32);
#pragma unroll
        for (int nt = 0; nt < 8; ++nt) {
            const short8 b = *(const short8*)(w2p + (((ks << 3) + nt) * 64 + lane) * 8);
            acc[nt] = __builtin_amdgcn_mfma_f32_16x16x32_bf16(a, b, acc[nt], 0, 0, 0);
        }
    }
    float s[8], sq[8];
    const int rowb = row0 + q * 4;
#pragma unroll
    for (int nt = 0; nt < 8; ++nt) {
        const float bias = b2[nt * 16 + l15];
        const int cc = nt * 16 + l15;
        float ls = 0.f, lq = 0.f;
#pragma unroll
        for (int reg = 0; reg < 4; ++reg) {
            const int r = rowb + reg;
            const float v = acc[nt][reg] + bias;
            if (r < N_NODES) {
                z2b[(size_t)r * HID + cc] = (unsigned short)f2bf(v);
                ls += v;
                lq = fmaf(v, v, lq);
            }
        }
        s[nt] = ls; sq[nt] = lq;
    }
#pragma unroll
    for (int nt = 0; nt < 8; ++nt) {
        s[nt] += __shfl_xor(s[nt], 16, 64);
        s[nt] += __shfl_xor(s[nt], 32, 64);
        sq[nt] += __shfl_xor(sq[nt], 16, 64);
        sq[nt] += __shfl_xor(sq[nt], 32, 64);
    }
    if (lane < 16) {
#pragma unroll
        for (int nt = 0; nt < 8; ++nt) {
            redA[w * 128 + nt * 16 + lane] = s[nt];
            redB[w * 128 + nt * 16 + lane] = sq[nt];
        }
    }
    __syncthreads();
    if (tid < 128) {
        float t = redA[tid] + redA[128 + tid] + redA[256 + tid] + redA[384 + tid];
        atomicAdd(&bn[tid], t);
    } else {
        const int c = tid - 128;
        float t = redB[c] + redB[128 + c] + redB[256 + c] + redB[384 + c];
        atomicAdd(&bn[128 + c], t);
    }
}

// ---------------------------------------------------------------------------
// Global add pool (batch sorted), fused last BN+ReLU. 64 threads/block,
// each handling a packed col pair (u32 loads); 64 nodes per block.
// ---------------------------------------------------------------------------
__global__ __launch_bounds__(64) void k_pool(const unsigned int* __restrict__ z2b32,
                                             const int* __restrict__ batch,
                                             const float* __restrict__ bnst,
                                             const float* __restrict__ gamma,
                                             const float* __restrict__ beta,
                                             float* __restrict__ g) {
    const int f = threadIdx.x;            // col pair (2f, 2f+1)
    const int f2 = f * 2;
    const float invN = 1.0f / (float)N_NODES;
    const float m0 = bnst[f2] * invN, m1 = bnst[f2 + 1] * invN;
    const float v0 = fmaxf(bnst[128 + f2] * invN - m0 * m0, 0.f);
    const float v1 = fmaxf(bnst[128 + f2 + 1] * invN - m1 * m1, 0.f);
    const float r0 = rsqrtf(v0 + BN_EPS), r1 = rsqrtf(v1 + BN_EPS);
    const float sc0 = gamma[f2] * r0, sc1 = gamma[f2 + 1] * r1;
    const float sh0 = fmaf(-m0, sc0, beta[f2]), sh1 = fmaf(-m1, sc1, beta[f2 + 1]);

    const int n0 = blockIdx.x * 64;       // grid 782: 782*64 = 50048 >= 50000
    if (n0 >= N_NODES) return;
    const int nend = min(n0 + 64, N_NODES);
    float a0 = 0.f, a1 = 0.f;
    int cur = batch[n0];
    for (int n = n0; n < nend; ++n) {
        const int bb = batch[n];
        if (bb != cur) {
            atomicAdd(&g[cur * HID + f2], a0);
            atomicAdd(&g[cur * HID + f2 + 1], a1);
            a0 = 0.f; a1 = 0.f;
            cur = bb;
        }
        const unsigned int u = z2b32[n * 64 + f];
        a0 += fmaxf(fmaf(bfl(u), sc0, sh0), 0.f);
        a1 += fmaxf(fmaf(bfh(u), sc1, sh1), 0.f);
    }
    atomicAdd(&g[cur * HID + f2], a0);
    atomicAdd(&g[cur * HID + f2 + 1], a1);
}

// ---------------------------------------------------------------------------
// Head: out = relu(g @ hW1 + hb1) @ hW2 + hb2, single block of 1024.
// ---------------------------------------------------------------------------
__global__ __launch_bounds__(1024) void k_head(const float* __restrict__ g,
                                               const float* __restrict__ W1h,
                                               const float* __restrict__ b1h,
                                               const float* __restrict__ W2h,
                                               const float* __restrict__ b2h,
                                               float* __restrict__ out) {
    __shared__ float g1s[NUM_GRAPHS * HID];
    const int tid = threadIdx.x;
#pragma unroll
    for (int i = 0; i < 8; ++i) {
        const int idx = i * 1024 + tid;       // 8192 outputs
        const int r = idx >> 7, c = idx & 127;
        float acc = b1h[c];
        for (int k = 0; k < 128; ++k) acc = fmaf(g[r * HID + k], W1h[k * HID + c], acc);
        g1s[idx] = fmaxf(acc, 0.f);
    }
    __syncthreads();
    if (tid < NUM_GRAPHS * 2) {
        const int r = tid >> 1, c = tid & 1;
        float acc = b2h[c];
        for (int k = 0; k < 128; ++k) acc = fmaf(g1s[r * HID + k], W2h[k * 2 + c], acc);
        out[tid] = acc;
    }
}

// ---------------------------------------------------------------------------
// Launch — 14 dispatches
// ---------------------------------------------------------------------------
extern "C" void kernel_launch(void* const* d_in, const int* in_sizes, int n_in,
                              void* d_out, int out_size, void* d_ws, size_t ws_size,
                              hipStream_t stream) {
    const float* x     = (const float*)d_in[0];
    const int*   ei    = (const int*)d_in[1];
    const float* eattr = (const float*)d_in[2];
    const int*   batch = (const int*)d_in[3];
    const float* encW  = (const float*)d_in[4];
    const float* encb  = (const float*)d_in[5];
    const float* eW    = (const float*)d_in[6];
    const float* eb    = (const float*)d_in[7];
    const float* W1    = (const float*)d_in[8];
    const float* b1    = (const float*)d_in[9];
    const float* W2    = (const float*)d_in[10];
    const float* b2    = (const float*)d_in[11];
    const float* gam   = (const float*)d_in[12];
    const float* bet   = (const float*)d_in[13];
    const float* hW1   = (const float*)d_in[14];
    const float* hb1   = (const float*)d_in[15];
    const float* hW2   = (const float*)d_in[16];
    const float* hb2   = (const float*)d_in[17];
    float* out = (float*)d_out;

    // workspace layout (float-sized slots)
    float* ws = (float*)d_ws;
    unsigned short* z2b = (unsigned short*)ws;              // 6.4M u16 = 3.2M floats
    float* bn0 = ws + 3200000;              // 256
    float* bn1 = ws + 3200256;              // 256
    float* g   = ws + 3200512;              // 8,192
    unsigned short* hb = (unsigned short*)(ws + 3216640);   // 6.4M u16
    unsigned int* zb32 = (unsigned int*)(ws + 6416640);     // 6.4M u16
    int* row_ptr = (int*)(ws + 11216640);   // 50,001
    int* cursor  = row_ptr + N_NODES + 1;   // 50,000
    int* bsums   = cursor + N_NODES;        // 256
    int* src_s   = bsums + 256;             // 640,000
    uint4* eattr_h = (uint4*)(ws + 12596900);               // 5.12M u32
    unsigned short* wp  = (unsigned short*)(ws + 17716900); // 98,304 u16
    unsigned short* wpe = (unsigned short*)(ws + 17766100); // 8,192 u16
    unsigned int*   wek = (unsigned int*)(ws + 17770200);   // 3,072 u32

    const int* esrc = ei;
    const int* edst = ei + N_EDGES;

    // pack weights + zero row_ptr/g (replaces 2 memsets)
    k_pack<<<292, 256, 0, stream>>>(W1, W2, encW, eW, wp, wpe, wek, g, row_ptr);
    // CSR build: hist -> hierarchical scan -> fused fill+materialize
    k_hist<<<N_EDGES / 256, 256, 0, stream>>>(edst, row_ptr);
    k_blockred<<<196, 256, 0, stream>>>(row_ptr, bsums);
    k_scan_bsums<<<1, 256, 0, stream>>>(bsums, 196);
    k_scan_blocks<<<196, 256, 0, stream>>>(row_ptr, bsums, cursor);
    k_fillg<<<N_EDGES / 256, 256, 0, stream>>>(esrc, edst, eattr, cursor, src_s, eattr_h);

    // encoder -> bf16 h (MFMA, reads fp32 x directly)
    k_encm<<<782, 256, 0, stream>>>(x, wpe, encb, hb);

    // per layer: agg (fused prev-BN+ReLU, zeroes next bn buffer) -> mlp
    float* bnbuf[2] = {bn0, bn1};
    for (int l = 0; l < N_LAYERS; ++l) {
        const unsigned int* in32 = (l == 0) ? (const unsigned int*)hb
                                            : (const unsigned int*)z2b;
        float* bnRead = bnbuf[(l + 1) & 1];   // stats written by mlp(l-1)
        float* bnZero = bnbuf[l & 1];         // buffer mlp(l) will accumulate into
        k_agg<<<12500, 256, 0, stream>>>(in32, src_s, eattr_h,
                                         wek + l * 1024, eb + l * HID, row_ptr,
                                         bnRead, gam + (l ? (l - 1) * HID : 0),
                                         bet + (l ? (l - 1) * HID : 0),
                                         (l > 0) ? 1 : 0, bnZero, zb32);
        k_mlp<<<782, 256, 0, stream>>>((const unsigned short*)zb32,
                                       wp + (size_t)l * 16384, b1 + l * HID,
                                       wp + (size_t)(3 + l) * 16384, b2 + l * HID,
                                       z2b, bnZero);
    }

    // pool (fused last BN+ReLU; mlp(2) wrote stats into bn0) -> head
    k_pool<<<782, 64, 0, stream>>>((const unsigned int*)z2b, batch, bn0,
                                   gam + 2 * HID, bet + 2 * HID, g);
    k_head<<<1, 1024, 0, stream>>>(g, hW1, hb1, hW2, hb2, out);
}